// Round 2
// baseline (308.517 us; speedup 1.0000x reference)
//
#include <hip/hip_runtime.h>

typedef __attribute__((ext_vector_type(8))) short short8;     // 8 x bf16 (4 VGPRs) MFMA frag
typedef __attribute__((ext_vector_type(4))) float floatx4;    // MFMA accumulator
typedef unsigned short u16;
typedef unsigned int   u32;

__device__ __forceinline__ u32 f2bf(float f) {               // fp32 -> bf16, round-to-nearest-even
  u32 u = __float_as_uint(f);
  return (u + 0x7fffu + ((u >> 16) & 1u)) >> 16;
}

__device__ __forceinline__ short8 cvt8(const float* f) {     // 8 fp32 -> bf16x8 fragment
  short8 r;
#pragma unroll
  for (int j = 0; j < 8; j++) r[j] = (short)f2bf(f[j]);
  return r;
}

// ---------------------------------------------------------------------------
// Householder precompute: one wave builds Q (64x64, fp32) sequentially,
// writes Q and Q^T as bf16 into workspace. Thread j owns column j in VGPRs.
// Q <- (I - 2 v v^T / (||v||^2 + 1e-8)) Q, applied for each of 32 rows of vs.
// ---------------------------------------------------------------------------
__global__ void __launch_bounds__(64) hh_kernel(const float* __restrict__ vs,
                                                u16* __restrict__ Qb,
                                                u16* __restrict__ Qtb) {
  const int j = threadIdx.x;
  float col[64];
#pragma unroll
  for (int i = 0; i < 64; i++) col[i] = (i == j) ? 1.f : 0.f;

  __shared__ float v[64];
#pragma unroll 1
  for (int r = 0; r < 32; r++) {
    __syncthreads();
    v[j] = vs[r * 64 + j];
    __syncthreads();
    // w[j] = sum_i v[i]*Q[i][j]  (thread-local, no cross-lane reduce)
    float vv0 = 0, vv1 = 0, vv2 = 0, vv3 = 0, w0 = 0, w1 = 0, w2 = 0, w3 = 0;
#pragma unroll
    for (int i = 0; i < 64; i += 4) {
      float a0 = v[i], a1 = v[i + 1], a2 = v[i + 2], a3 = v[i + 3];
      vv0 += a0 * a0; vv1 += a1 * a1; vv2 += a2 * a2; vv3 += a3 * a3;
      w0 += a0 * col[i]; w1 += a1 * col[i + 1]; w2 += a2 * col[i + 2]; w3 += a3 * col[i + 3];
    }
    float coef = 2.f / (((vv0 + vv1) + (vv2 + vv3)) + 1e-8f);
    float cw = coef * ((w0 + w1) + (w2 + w3));
#pragma unroll
    for (int i = 0; i < 64; i++) col[i] -= v[i] * cw;
  }
#pragma unroll
  for (int i = 0; i < 64; i++) {
    Qb [i * 64 + j] = (u16)f2bf(col[i]);   // Qb[i][j]  = Q[i][j]
    Qtb[j * 64 + i] = (u16)f2bf(col[i]);   // Qtb[o][i] = Q[i][o]
  }
}

// ---------------------------------------------------------------------------
// Main kernel. One wave processes a 16-token tile:
//   GEMM1: qi^T = Q * x^T       (A = Q rows [regs], B = token rows, fp32->bf16)
//   RoPE : lane-local fp32 (D layout: col=lane&15 -> token, row=quad*4+r -> feature)
//   GEMM2: out^T = Q^T * qr^T   (A = Qt rows [regs], B = qr via bf16 LDS round-trip)
//   Store: fp32.
// B=4 H=16 S=4096 D=64; tokens per tensor = 262144; tiles = 2*16384 = 32768.
// ---------------------------------------------------------------------------
__global__ void __launch_bounds__(256) rnrope_kernel(
    const float* __restrict__ qp, const float* __restrict__ kp,
    const float* __restrict__ cosp, const float* __restrict__ sinp,
    const u16* __restrict__ Qb, const u16* __restrict__ Qtb,
    float* __restrict__ outp) {
  const int lane = threadIdx.x & 63;
  const int t    = lane & 15;    // token within tile (B-operand n / D col)
  const int quad = lane >> 4;    // k-subblock selector
  const int wave = blockIdx.x * 4 + (threadIdx.x >> 6);

  __shared__ alignas(16) u16 sh_all[4][1152];  // per-wave 16 rows x stride 72 (2-way-conflict free)
  u16* sh = sh_all[threadIdx.x >> 6];

  // Constant A-operand fragments: A[m=lane&15][k=quad*8+j], 16B contiguous per lane.
  short8 aQ[4][2], aT[4][2];
#pragma unroll
  for (int i0 = 0; i0 < 4; i0++) {
#pragma unroll
    for (int ks = 0; ks < 2; ks++) {
      aQ[i0][ks] = *(const short8*)(Qb  + (i0 * 16 + t) * 64 + ks * 32 + quad * 8);
      aT[i0][ks] = *(const short8*)(Qtb + (i0 * 16 + t) * 64 + ks * 32 + quad * 8);
    }
  }

#pragma unroll 1
  for (int it = 0; it < 4; ++it) {
    const int tile = wave * 4 + it;                 // 0..32767
    const int tt   = tile & 16383;
    const bool isq = (tile < 16384);
    const float* __restrict__ inp = isq ? qp : kp;
    float* __restrict__ op = outp + (isq ? 0 : 16777216);
    const int token_base = tt * 16;
    const int s = token_base & 4095;                // tile never crosses (b,h) boundary
    const int b = token_base >> 16;                 // 65536 tokens per b
    const int csoff = ((b << 12) + s + t) * 64;     // cos/sin row for this lane's token
    const float* crow = cosp + csoff;
    const float* srow = sinp + csoff;
    const float* xrow = inp + (token_base + t) * 64;

    // B fragments of GEMM1: B[k=quad*8+j][n=t] = x[t][k]; 32B fp32 per lane per frag.
    float xb[16];
    *(float4*)&xb[0]  = *(const float4*)(xrow + quad * 8);
    *(float4*)&xb[4]  = *(const float4*)(xrow + quad * 8 + 4);
    *(float4*)&xb[8]  = *(const float4*)(xrow + 32 + quad * 8);
    *(float4*)&xb[12] = *(const float4*)(xrow + 32 + quad * 8 + 4);
    short8 bq0 = cvt8(&xb[0]);   // k = 0..31
    short8 bq1 = cvt8(&xb[8]);   // k = 32..63

    // GEMM1: qi[t][i], i = i0*16 + quad*4 + r
    floatx4 acc[4];
#pragma unroll
    for (int i0 = 0; i0 < 4; i0++) {
      floatx4 z = {0.f, 0.f, 0.f, 0.f};
      z = __builtin_amdgcn_mfma_f32_16x16x32_bf16(aQ[i0][0], bq0, z, 0, 0, 0);
      z = __builtin_amdgcn_mfma_f32_16x16x32_bf16(aQ[i0][1], bq1, z, 0, 0, 0);
      acc[i0] = z;
    }

    // cos/sin: 4 contiguous fp32 per (i0,quad) -> float4 loads
    float4 c[4], sn[4];
#pragma unroll
    for (int i0 = 0; i0 < 4; i0++) {
      c [i0] = *(const float4*)(crow + i0 * 16 + quad * 4);
      sn[i0] = *(const float4*)(srow + i0 * 16 + quad * 4);
    }

    // RoPE (lane-local; partner feature i±32 lives in tile i0^2, same reg) + pack bf16 to LDS
#pragma unroll
    for (int i0 = 0; i0 < 4; i0++) {
      const int p = i0 ^ 2;
      const float sg = (i0 < 2) ? -1.f : 1.f;   // i<32: -x2*sin ; i>=32: +x1*sin
      float r0 = acc[i0][0] * c[i0].x + sg * acc[p][0] * sn[i0].x;
      float r1 = acc[i0][1] * c[i0].y + sg * acc[p][1] * sn[i0].y;
      float r2 = acc[i0][2] * c[i0].z + sg * acc[p][2] * sn[i0].z;
      float r3 = acc[i0][3] * c[i0].w + sg * acc[p][3] * sn[i0].w;
      u32 lo = f2bf(r0) | (f2bf(r1) << 16);
      u32 hi = f2bf(r2) | (f2bf(r3) << 16);
      *(uint2*)&sh[t * 72 + i0 * 16 + quad * 4] = make_uint2(lo, hi);  // qr[t][i..i+3]
    }

    __builtin_amdgcn_wave_barrier();   // wave-synchronous LDS: DS pipe is in-order per wave
    short8 br0 = *(const short8*)&sh[t * 72 + quad * 8];        // B[k=quad*8+j][n=t], k 0..31
    short8 br1 = *(const short8*)&sh[t * 72 + 32 + quad * 8];   // k 32..63

    // GEMM2 + store: out[t][o], o = o0*16 + quad*4 + r (4 contiguous fp32 -> float4 store)
#pragma unroll
    for (int o0 = 0; o0 < 4; o0++) {
      floatx4 z = {0.f, 0.f, 0.f, 0.f};
      z = __builtin_amdgcn_mfma_f32_16x16x32_bf16(aT[o0][0], br0, z, 0, 0, 0);
      z = __builtin_amdgcn_mfma_f32_16x16x32_bf16(aT[o0][1], br1, z, 0, 0, 0);
      float4 st = make_float4(z[0], z[1], z[2], z[3]);
      *(float4*)(op + (token_base + t) * 64 + o0 * 16 + quad * 4) = st;
    }
    __builtin_amdgcn_wave_barrier();
  }
}

extern "C" void kernel_launch(void* const* d_in, const int* in_sizes, int n_in,
                              void* d_out, int out_size, void* d_ws, size_t ws_size,
                              hipStream_t stream) {
  const float* q    = (const float*)d_in[0];
  const float* k    = (const float*)d_in[1];
  const float* cosp = (const float*)d_in[2];
  const float* sinp = (const float*)d_in[3];
  const float* vs   = (const float*)d_in[4];
  float* out = (float*)d_out;
  u16* Qb  = (u16*)d_ws;          // 64x64 bf16 Q
  u16* Qtb = Qb + 4096;           // 64x64 bf16 Q^T

  hipLaunchKernelGGL(hh_kernel, dim3(1), dim3(64), 0, stream, vs, Qb, Qtb);
  hipLaunchKernelGGL(rnrope_kernel, dim3(2048), dim3(256), 0, stream,
                     q, k, cosp, sinp, Qb, Qtb, out);
}